// Round 4
// baseline (517.138 us; speedup 1.0000x reference)
//
#include <hip/hip_runtime.h>
#include <math.h>

// ---------------------------------------------------------------------------
// Restormer block, B=1 DIM=3 NC=512 HEADS=2 -> CT=768, NT=32, HID=6. f32 I/O.
//
// conv3x3 (+) MLP-stage1 collapsed through G[ci,h,dx,n] = row-correlations of
// x with w1 columns (1.8 MB instead of the 805 MB conv output t).
// R3/R4: k_mlp rebuilt — LDS-staged G shared by 9 channels/block (9x less L2
// traffic), rolling 3-row register taps (9 ds_reads/h instead of 27), 4-way
// h-split for occupancy (1032 blocks) with atomicAdd into pre-sigmoid PS,
// epilogue split into k_mlp2. k_prep S1 wave-parallel. k_av retiled 32x64.
// R4 fixes the unbalanced fmaxf tree in k_soft (compile error in R3).
// ---------------------------------------------------------------------------

__device__ __forceinline__ float sigm(float s) {
    return __builtin_amdgcn_rcpf(1.f + __expf(-s));
}

// ---- f32 workspace layout (element offsets) -------------------------------
static constexpr int OFF_G   = 0;         // [3v][515 rows][3ci][3dx][32n]; rows 0,513,514 zero pad
static constexpr int GSTRIDE = 148320;    // 515*288
static constexpr int OFF_S1  = 444960;    // [3v][32] column sums of w1
static constexpr int OFF_QKV = 445056;    // [3v][4head][768c][256s]
static constexpr int OFF_SC  = 2804352;   // [4head][768][768]; ALSO pre-sigmoid PS [3v][768c][32o][32n]
static constexpr int OFF_ATT = 5163648;   // [4head][768][256] == (3,512,512) flat
// total 5950080 floats = 23.8 MB

// ---------------------------------------------------------------------------
// k_prep: zero G pad rows; S1[v][n] = sum_u w1v[u][n] (one wave per (v,n));
// zero the PS accumulator (overlaid on OFF_SC).
// ---------------------------------------------------------------------------
__global__ __launch_bounds__(256) void k_prep(const float* __restrict__ qw1,
                                              const float* __restrict__ kw1,
                                              const float* __restrict__ vw1,
                                              float* __restrict__ ws) {
    int i = blockIdx.x * 256 + threadIdx.x;
    if (i < 2592) {                        // zero G pad rows 0,513,514 per v
        int v = i / 864, rr = (i % 864) / 288, col = i % 288;
        int row = (rr == 0) ? 0 : (512 + rr);
        ws[OFF_G + v * GSTRIDE + row * 288 + col] = 0.f;
    } else if (i >= 2624 && i < 8768) {    // S1: 96 waves, shuffle-reduce
        int j = i - 2624;
        int w = j >> 6, lane = j & 63;
        int v = w >> 5, n = w & 31;
        const float* w1p = (v == 0) ? qw1 : ((v == 1) ? kw1 : vw1);
        float s = 0.f;
#pragma unroll
        for (int k = 0; k < 8; k++) s += w1p[(lane + 64 * k) * 32 + n];
#pragma unroll
        for (int off = 32; off > 0; off >>= 1) s += __shfl_xor(s, off);
        if (lane == 0) ws[OFF_S1 + w] = s;
    } else if (i >= 8768 && i < 8768 + 2359296) {
        ws[OFF_SC + (i - 8768)] = 0.f;     // PS init
    }
}

// ---------------------------------------------------------------------------
// k_corr: G[v][h+1][ci][dx][n] = sum_u x[ci][h][u] * w1v[u+1-dx][n]
// grid (64 hblk, 3 ci, 3 v), block 256 = 8 rows x 32 n.
// ---------------------------------------------------------------------------
__global__ __launch_bounds__(256) void k_corr(const float* __restrict__ x,
                                              const float* __restrict__ qw1,
                                              const float* __restrict__ kw1,
                                              const float* __restrict__ vw1,
                                              float* __restrict__ ws) {
    const int h0 = blockIdx.x * 8, ci = blockIdx.y, v = blockIdx.z;
    const int tid = threadIdx.x;
    __shared__ __align__(16) float ws1t[32 * 516];

    const float* w1f = (v == 0) ? qw1 : ((v == 1) ? kw1 : vw1);
    for (int i = tid; i < 4096; i += 256) {       // transpose-stage w1
        int n_ = i & 31, u = (i >> 5) * 4;
        float a = w1f[(u + 0) * 32 + n_];
        float b = w1f[(u + 1) * 32 + n_];
        float c = w1f[(u + 2) * 32 + n_];
        float d = w1f[(u + 3) * 32 + n_];
        *(float4*)&ws1t[n_ * 516 + u] = make_float4(a, b, c, d);
    }
    if (tid < 32) *(float4*)&ws1t[tid * 516 + 512] = make_float4(0.f, 0.f, 0.f, 0.f);
    __syncthreads();

    const int hp = tid >> 5, n = tid & 31;
    const float* xrow = x + ci * 262144 + (h0 + hp) * 512;
    float a0 = 0.f, a1 = 0.f, a2 = 0.f, pq = 0.f;
    float4 cq = *(float4*)&ws1t[n * 516];
#pragma unroll 4
    for (int k = 0; k < 128; k++) {
        float4 nq = *(float4*)&ws1t[n * 516 + 4 * k + 4];
        float4 x4 = *(const float4*)&xrow[4 * k];
        a1 = fmaf(x4.x, cq.x, a1); a1 = fmaf(x4.y, cq.y, a1);
        a1 = fmaf(x4.z, cq.z, a1); a1 = fmaf(x4.w, cq.w, a1);
        a0 = fmaf(x4.x, cq.y, a0); a0 = fmaf(x4.y, cq.z, a0);
        a0 = fmaf(x4.z, cq.w, a0); a0 = fmaf(x4.w, nq.x, a0);
        a2 = fmaf(x4.x, pq,   a2); a2 = fmaf(x4.y, cq.x, a2);
        a2 = fmaf(x4.z, cq.y, a2); a2 = fmaf(x4.w, cq.z, a2);
        pq = cq.w; cq = nq;
    }
    float* g = ws + OFF_G + v * GSTRIDE + (h0 + hp + 1) * 288 + ci * 96 + n;
    g[0] = a0; g[32] = a1; g[64] = a2;
}

// ---------------------------------------------------------------------------
// k_mlp: per (v, c): y1[h,n] = sigm(b1 + cb*S1 + 27-tap gather), partial
// stage-2 sum over a 128-row h chunk, atomicAdd into PS[v][c][o][n].
// grid (86 cblk, 4 hchunk, 3 v), block 320 (9 channels x 32 n).
// ---------------------------------------------------------------------------
struct MlpPtrs {
    const float* b1[3];
    const float* w2[3];
    const float* b2[3];
};

__global__ __launch_bounds__(320) void k_mlp(const float* __restrict__ cwp,
                                             const float* __restrict__ cbp,
                                             MlpPtrs mp, float* __restrict__ ws) {
    const int cb = blockIdx.x, hc = blockIdx.y, v = blockIdx.z;
    const int tid = threadIdx.x, cl = tid >> 5, n = tid & 31;
    const int c = cb * 9 + cl;
    const bool active = (cl < 9) && (c < 768);
    __shared__ __align__(16) float gs[34 * 288];

    const float* gv  = ws + OFF_G + v * GSTRIDE;
    const float* w2p = mp.w2[v];

    float cwr[3][9];
    float base = 0.f;
    if (active) {
#pragma unroll
        for (int dy = 0; dy < 3; dy++)
#pragma unroll
            for (int q = 0; q < 9; q++)
                cwr[dy][q] = cwp[c * 27 + (q / 3) * 9 + dy * 3 + (q % 3)];
        base = mp.b1[v][n] + cbp[c] * ws[OFF_S1 + v * 32 + n];
    }

    float acc[32];
#pragma unroll
    for (int o = 0; o < 32; o++) acc[o] = 0.f;

    for (int s = 0; s < 4; s++) {
        const int row0 = hc * 128 + s * 32;     // G rows row0..row0+33 (<=513, pads ok)
        __syncthreads();
        for (int t = tid; t < 2448; t += 320) { // 34 rows x 72 float4
            int r = t / 72, cc = t % 72;
            *(float4*)&gs[r * 288 + cc * 4] = *(const float4*)&gv[(row0 + r) * 288 + cc * 4];
        }
        __syncthreads();
        if (active) {
            float R[3][9];
#pragma unroll
            for (int q = 0; q < 9; q++) {
                int off = (q / 3) * 96 + (q % 3) * 32 + n;
                R[0][q] = gs[off];
                R[1][q] = gs[288 + off];
            }
#pragma unroll
            for (int hl = 0; hl < 32; hl++) {
#pragma unroll
                for (int q = 0; q < 9; q++)
                    R[(hl + 2) % 3][q] = gs[(hl + 2) * 288 + (q / 3) * 96 + (q % 3) * 32 + n];
                float s0 = base, s1 = 0.f, s2 = 0.f;
#pragma unroll
                for (int q = 0; q < 9; q++) {
                    s0 = fmaf(cwr[0][q], R[hl % 3][q],       s0);
                    s1 = fmaf(cwr[1][q], R[(hl + 1) % 3][q], s1);
                    s2 = fmaf(cwr[2][q], R[(hl + 2) % 3][q], s2);
                }
                float y = sigm((s0 + s1) + s2);
                const float* w2row = w2p + (row0 + hl) * 32;   // wave-uniform -> s_load
#pragma unroll
                for (int o = 0; o < 32; o++) acc[o] = fmaf(y, w2row[o], acc[o]);
            }
        }
    }

    if (active) {
        float* ps = ws + OFF_SC + ((v * 768 + c) * 32) * 32;   // [o][n]
#pragma unroll
        for (int o = 0; o < 32; o++) atomicAdd(&ps[o * 32 + n], acc[o]);
    }
}

// ---------------------------------------------------------------------------
// k_mlp2: PS -> +b2 -> sigmoid -> split-heads scatter into QKV.
// ---------------------------------------------------------------------------
__global__ __launch_bounds__(256) void k_mlp2(MlpPtrs mp, float* __restrict__ ws) {
    int i = blockIdx.x * 256 + threadIdx.x;       // over 3*768*32*32
    if (i >= 2359296) return;
    int n = i & 31, o = (i >> 5) & 31;
    int cv = i >> 10;                              // 0..2303
    int c = cv % 768, v = cv / 768;
    float m = sigm(ws[OFF_SC + i] + mp.b2[v][o]);
    int head = ((o & 1) << 1) | (n & 1);           // (head1,head2)
    int sidx = ((o >> 1) << 4) | (n >> 1);         // hidx*16+widx
    ws[OFF_QKV + v * 786432 + head * 196608 + c * 256 + sidx] = m;
}

// ---------------------------------------------------------------------------
// k_qk: scores[head] = temp[head] * Q @ K^T   (768x768, K=256)
// 64x64 tiles, 4x4 micro-tile, LDS tiles stored [k][row] for b128 reads.
// ---------------------------------------------------------------------------
__global__ __launch_bounds__(256) void k_qk(const float* __restrict__ tempr,
                                            float* __restrict__ ws) {
    const int i0 = blockIdx.x * 64, j0 = blockIdx.y * 64, head = blockIdx.z;
    const float* Q = ws + OFF_QKV + head * 196608;             // v=0
    const float* K = ws + OFF_QKV + 786432 + head * 196608;    // v=1
    float* S = ws + OFF_SC + head * 589824;
    const float temp = tempr[head];
    __shared__ __align__(16) float Qs[64][68];
    __shared__ __align__(16) float Ks[64][68];
    const int tid = threadIdx.x, ty = tid >> 4, tx = tid & 15;
    float acc[4][4] = {};

    for (int kc = 0; kc < 256; kc += 64) {
        __syncthreads();
        for (int idx = tid; idx < 1024; idx += 256) {
            int r = idx >> 4, k4 = (idx & 15) * 4;
            float4 q = *(const float4*)&Q[(i0 + r) * 256 + kc + k4];
            Qs[k4 + 0][r] = q.x; Qs[k4 + 1][r] = q.y; Qs[k4 + 2][r] = q.z; Qs[k4 + 3][r] = q.w;
            float4 k = *(const float4*)&K[(j0 + r) * 256 + kc + k4];
            Ks[k4 + 0][r] = k.x; Ks[k4 + 1][r] = k.y; Ks[k4 + 2][r] = k.z; Ks[k4 + 3][r] = k.w;
        }
        __syncthreads();
#pragma unroll
        for (int k = 0; k < 64; k++) {
            float4 a = *(float4*)&Qs[k][ty * 4];
            float4 b = *(float4*)&Ks[k][tx * 4];
            float av[4] = {a.x, a.y, a.z, a.w}, bv[4] = {b.x, b.y, b.z, b.w};
#pragma unroll
            for (int e = 0; e < 4; e++)
#pragma unroll
                for (int f = 0; f < 4; f++) acc[e][f] = fmaf(av[e], bv[f], acc[e][f]);
        }
    }
#pragma unroll
    for (int e = 0; e < 4; e++) {
        float4 r = make_float4(acc[e][0] * temp, acc[e][1] * temp,
                               acc[e][2] * temp, acc[e][3] * temp);
        *(float4*)&S[(i0 + ty * 4 + e) * 768 + j0 + tx * 4] = r;
    }
}

// ---------------------------------------------------------------------------
// k_soft: row softmax over 768. One wave per row.
// ---------------------------------------------------------------------------
__global__ __launch_bounds__(64) void k_soft(float* __restrict__ ws) {
    float* row = ws + OFF_SC + (size_t)blockIdx.x * 768;
    const int t = threadIdx.x;
    float4 v0 = *(float4*)&row[t * 12];
    float4 v1 = *(float4*)&row[t * 12 + 4];
    float4 v2 = *(float4*)&row[t * 12 + 8];
    float m0 = fmaxf(fmaxf(v0.x, v0.y), fmaxf(v0.z, v0.w));
    float m1 = fmaxf(fmaxf(v1.x, v1.y), fmaxf(v1.z, v1.w));
    float m2 = fmaxf(fmaxf(v2.x, v2.y), fmaxf(v2.z, v2.w));
    float m = fmaxf(fmaxf(m0, m1), m2);
#pragma unroll
    for (int off = 32; off > 0; off >>= 1) m = fmaxf(m, __shfl_xor(m, off));
    v0.x = __expf(v0.x - m); v0.y = __expf(v0.y - m); v0.z = __expf(v0.z - m); v0.w = __expf(v0.w - m);
    v1.x = __expf(v1.x - m); v1.y = __expf(v1.y - m); v1.z = __expf(v1.z - m); v1.w = __expf(v1.w - m);
    v2.x = __expf(v2.x - m); v2.y = __expf(v2.y - m); v2.z = __expf(v2.z - m); v2.w = __expf(v2.w - m);
    float s = v0.x + v0.y + v0.z + v0.w + v1.x + v1.y + v1.z + v1.w + v2.x + v2.y + v2.z + v2.w;
#pragma unroll
    for (int off = 32; off > 0; off >>= 1) s += __shfl_xor(s, off);
    float inv = __builtin_amdgcn_rcpf(s);
    v0.x *= inv; v0.y *= inv; v0.z *= inv; v0.w *= inv;
    v1.x *= inv; v1.y *= inv; v1.z *= inv; v1.w *= inv;
    v2.x *= inv; v2.y *= inv; v2.z *= inv; v2.w *= inv;
    *(float4*)&row[t * 12]     = v0;
    *(float4*)&row[t * 12 + 4] = v1;
    *(float4*)&row[t * 12 + 8] = v2;
}

// ---------------------------------------------------------------------------
// k_av: ATT[head] = attn @ V  (768x256, K=768). 32x64 tiles (384 blocks),
// 2x4 micro-tile.
// ---------------------------------------------------------------------------
__global__ __launch_bounds__(256) void k_av(float* __restrict__ ws) {
    const int i0 = blockIdx.x * 32, s0 = blockIdx.y * 64, head = blockIdx.z;
    const float* A = ws + OFF_SC + head * 589824;
    const float* V = ws + OFF_QKV + 2 * 786432 + head * 196608;
    float* O = ws + OFF_ATT + head * 196608;
    __shared__ __align__(16) float As[64][34];
    __shared__ __align__(16) float Bs[64][68];
    const int tid = threadIdx.x, ty = tid >> 4, tx = tid & 15;
    float acc[2][4] = {};

    for (int dc = 0; dc < 768; dc += 64) {
        __syncthreads();
        for (int idx = tid; idx < 512; idx += 256) {
            int r = idx >> 4, k4 = (idx & 15) * 4;
            float4 a = *(const float4*)&A[(i0 + r) * 768 + dc + k4];
            As[k4 + 0][r] = a.x; As[k4 + 1][r] = a.y; As[k4 + 2][r] = a.z; As[k4 + 3][r] = a.w;
        }
        for (int idx = tid; idx < 1024; idx += 256) {
            int r = idx >> 4, k4 = (idx & 15) * 4;
            *(float4*)&Bs[r][k4] = *(const float4*)&V[(dc + r) * 256 + s0 + k4];
        }
        __syncthreads();
#pragma unroll
        for (int k = 0; k < 64; k++) {
            float a0 = As[k][ty * 2], a1 = As[k][ty * 2 + 1];
            float4 b = *(float4*)&Bs[k][tx * 4];
            acc[0][0] = fmaf(a0, b.x, acc[0][0]); acc[0][1] = fmaf(a0, b.y, acc[0][1]);
            acc[0][2] = fmaf(a0, b.z, acc[0][2]); acc[0][3] = fmaf(a0, b.w, acc[0][3]);
            acc[1][0] = fmaf(a1, b.x, acc[1][0]); acc[1][1] = fmaf(a1, b.y, acc[1][1]);
            acc[1][2] = fmaf(a1, b.z, acc[1][2]); acc[1][3] = fmaf(a1, b.w, acc[1][3]);
        }
    }
#pragma unroll
    for (int e = 0; e < 2; e++) {
        float4 r = make_float4(acc[e][0], acc[e][1], acc[e][2], acc[e][3]);
        *(float4*)&O[(i0 + ty * 2 + e) * 256 + s0 + tx * 4] = r;
    }
}

// ---------------------------------------------------------------------------
// k_ffn: fused pointwise(3->12) + dwconv3x3 + gelu-gate + pointwise(6->3)
// + residual, f32 store. 32x32 pixel tiles, 34x34 halo in LDS.
// ---------------------------------------------------------------------------
struct FfnPtrs { const float* p[6]; };  // pi_w, pi_b, dw_w, dw_b, po_w, po_b

__global__ __launch_bounds__(256) void k_ffn(const float* __restrict__ ws,
                                             const float* __restrict__ x,
                                             FfnPtrs fp,
                                             float* __restrict__ out) {
    const int x0 = blockIdx.x * 32, y0 = blockIdx.y * 32;
    __shared__ float wsm[192];
    __shared__ float p[12][1156];
    const int tid = threadIdx.x;
    if (tid < 36)       wsm[tid] = fp.p[0][tid];          // pi_w (12,3)
    else if (tid < 48)  wsm[tid] = fp.p[1][tid - 36];     // pi_b (12)
    else if (tid < 156) wsm[tid] = fp.p[2][tid - 48];     // dw_w (12,9)
    else if (tid < 168) wsm[tid] = fp.p[3][tid - 156];    // dw_b (12)
    else if (tid < 186) wsm[tid] = fp.p[4][tid - 168];    // po_w (3,6)
    else if (tid < 189) wsm[tid] = fp.p[5][tid - 186];    // po_b (3)
    __syncthreads();

    const float* A = ws + OFF_ATT;
    for (int i = tid; i < 1156; i += 256) {
        int py = i / 34, px = i % 34;
        int gy = y0 + py - 1, gx = x0 + px - 1;
        bool in = ((unsigned)gy < 512u) && ((unsigned)gx < 512u);
        float a0 = 0.f, a1 = 0.f, a2 = 0.f;
        if (in) {
            int b = gy * 512 + gx;
            a0 = A[b]; a1 = A[262144 + b]; a2 = A[524288 + b];
        }
#pragma unroll
        for (int j = 0; j < 12; j++) {
            float t = in ? (wsm[36 + j] + wsm[j * 3] * a0 + wsm[j * 3 + 1] * a1
                            + wsm[j * 3 + 2] * a2)
                         : 0.f;
            p[j][i] = t;
        }
    }
    __syncthreads();

#pragma unroll
    for (int it = 0; it < 4; it++) {
        int pl = tid + it * 256;
        int ly = pl >> 5, lx = pl & 31;
        float z[12];
#pragma unroll
        for (int j = 0; j < 12; j++) {
            const float* dw = &wsm[48 + j * 9];
            const float* pr = &p[j][ly * 34 + lx];
            z[j] = wsm[156 + j]
                 + dw[0] * pr[0]  + dw[1] * pr[1]  + dw[2] * pr[2]
                 + dw[3] * pr[34] + dw[4] * pr[35] + dw[5] * pr[36]
                 + dw[6] * pr[68] + dw[7] * pr[69] + dw[8] * pr[70];
        }
        float g[6];
#pragma unroll
        for (int j = 0; j < 6; j++) {
            float xx = z[j];
            g[j] = 0.5f * xx * (1.f + erff(xx * 0.70710678118f)) * z[6 + j];
        }
        int b = (y0 + ly) * 512 + (x0 + lx);
#pragma unroll
        for (int co = 0; co < 3; co++) {
            float r = wsm[186 + co];
#pragma unroll
            for (int j = 0; j < 6; j++) r = fmaf(wsm[168 + co * 6 + j], g[j], r);
            r += x[co * 262144 + b];             // residual
            out[co * 262144 + b] = r;
        }
    }
}

// ---------------------------------------------------------------------------
extern "C" void kernel_launch(void* const* d_in, const int* in_sizes, int n_in,
                              void* d_out, int out_size, void* d_ws, size_t ws_size,
                              hipStream_t stream) {
    float* ws = (float*)d_ws;
    float* out = (float*)d_out;
    const float* x   = (const float*)d_in[0];
    const float* cw  = (const float*)d_in[1];
    const float* cb  = (const float*)d_in[2];
    const float* qw1 = (const float*)d_in[3];
    const float* kw1 = (const float*)d_in[7];
    const float* vw1 = (const float*)d_in[11];
    const float* temp= (const float*)d_in[15];

    MlpPtrs mp;
    mp.b1[0] = (const float*)d_in[4];  mp.w2[0] = (const float*)d_in[5];  mp.b2[0] = (const float*)d_in[6];
    mp.b1[1] = (const float*)d_in[8];  mp.w2[1] = (const float*)d_in[9];  mp.b2[1] = (const float*)d_in[10];
    mp.b1[2] = (const float*)d_in[12]; mp.w2[2] = (const float*)d_in[13]; mp.b2[2] = (const float*)d_in[14];

    FfnPtrs fp;
    for (int i = 0; i < 6; i++) fp.p[i] = (const float*)d_in[16 + i];

    k_prep<<<9251, 256, 0, stream>>>(qw1, kw1, vw1, ws);
    k_corr<<<dim3(64, 3, 3), 256, 0, stream>>>(x, qw1, kw1, vw1, ws);
    k_mlp <<<dim3(86, 4, 3), 320, 0, stream>>>(cw, cb, mp, ws);
    k_mlp2<<<9216, 256, 0, stream>>>(mp, ws);
    k_qk  <<<dim3(12, 12, 4), 256, 0, stream>>>(temp, ws);
    k_soft<<<3072, 64, 0, stream>>>(ws);
    k_av  <<<dim3(24, 4, 4), 256, 0, stream>>>(ws);
    k_ffn <<<dim3(16, 16), 256, 0, stream>>>(ws, x, fp, out);
}

// Round 5
// 344.017 us; speedup vs baseline: 1.5032x; 1.5032x over previous
//
#include <hip/hip_runtime.h>
#include <math.h>

// ---------------------------------------------------------------------------
// Restormer block, B=1 DIM=3 NC=512 HEADS=2 -> CT=768, NT=32, HID=6. f32 I/O.
//
// conv3x3 (+) MLP-stage1 collapsed through G[ci,h,dx,n] = row-correlations of
// x with w1 columns (1.8 MB instead of the 805 MB conv output t).
// R5: k_mlp latency fix — NO LDS (taps straight from L1-resident G; LDS cap
// was pinning co-residency to 1 block/CU), 256-thr blocks, grid (96,4,3) =
// 1152 blocks -> ~16 waves/CU, and w2 rows software-pipelined one row ahead
// so the scalar-load lgkm wait overlaps the tap FMAs.
// ---------------------------------------------------------------------------

__device__ __forceinline__ float sigm(float s) {
    return __builtin_amdgcn_rcpf(1.f + __expf(-s));
}

// ---- f32 workspace layout (element offsets) -------------------------------
static constexpr int OFF_G   = 0;         // [3v][515 rows][3ci][3dx][32n]; rows 0,513,514 zero pad
static constexpr int GSTRIDE = 148320;    // 515*288
static constexpr int OFF_S1  = 444960;    // [3v][32] column sums of w1
static constexpr int OFF_QKV = 445056;    // [3v][4head][768c][256s]
static constexpr int OFF_SC  = 2804352;   // [4head][768][768]; ALSO pre-sigmoid PS [3v][768c][32o][32n]
static constexpr int OFF_ATT = 5163648;   // [4head][768][256] == (3,512,512) flat
// total 5950080 floats = 23.8 MB

// ---------------------------------------------------------------------------
// k_prep: zero G pad rows; S1[v][n] = sum_u w1v[u][n]; zero PS accumulator.
// ---------------------------------------------------------------------------
__global__ __launch_bounds__(256) void k_prep(const float* __restrict__ qw1,
                                              const float* __restrict__ kw1,
                                              const float* __restrict__ vw1,
                                              float* __restrict__ ws) {
    int i = blockIdx.x * 256 + threadIdx.x;
    if (i < 2592) {                        // zero G pad rows 0,513,514 per v
        int v = i / 864, rr = (i % 864) / 288, col = i % 288;
        int row = (rr == 0) ? 0 : (512 + rr);
        ws[OFF_G + v * GSTRIDE + row * 288 + col] = 0.f;
    } else if (i >= 2624 && i < 8768) {    // S1: 96 waves, shuffle-reduce
        int j = i - 2624;
        int w = j >> 6, lane = j & 63;
        int v = w >> 5, n = w & 31;
        const float* w1p = (v == 0) ? qw1 : ((v == 1) ? kw1 : vw1);
        float s = 0.f;
#pragma unroll
        for (int k = 0; k < 8; k++) s += w1p[(lane + 64 * k) * 32 + n];
#pragma unroll
        for (int off = 32; off > 0; off >>= 1) s += __shfl_xor(s, off);
        if (lane == 0) ws[OFF_S1 + w] = s;
    } else if (i >= 8768 && i < 8768 + 2359296) {
        ws[OFF_SC + (i - 8768)] = 0.f;     // PS init
    }
}

// ---------------------------------------------------------------------------
// k_corr: G[v][h+1][ci][dx][n] = sum_u x[ci][h][u] * w1v[u+1-dx][n]
// grid (64 hblk, 3 ci, 3 v), block 256 = 8 rows x 32 n.
// ---------------------------------------------------------------------------
__global__ __launch_bounds__(256) void k_corr(const float* __restrict__ x,
                                              const float* __restrict__ qw1,
                                              const float* __restrict__ kw1,
                                              const float* __restrict__ vw1,
                                              float* __restrict__ ws) {
    const int h0 = blockIdx.x * 8, ci = blockIdx.y, v = blockIdx.z;
    const int tid = threadIdx.x;
    __shared__ __align__(16) float ws1t[32 * 516];

    const float* w1f = (v == 0) ? qw1 : ((v == 1) ? kw1 : vw1);
    for (int i = tid; i < 4096; i += 256) {       // transpose-stage w1
        int n_ = i & 31, u = (i >> 5) * 4;
        float a = w1f[(u + 0) * 32 + n_];
        float b = w1f[(u + 1) * 32 + n_];
        float c = w1f[(u + 2) * 32 + n_];
        float d = w1f[(u + 3) * 32 + n_];
        *(float4*)&ws1t[n_ * 516 + u] = make_float4(a, b, c, d);
    }
    if (tid < 32) *(float4*)&ws1t[tid * 516 + 512] = make_float4(0.f, 0.f, 0.f, 0.f);
    __syncthreads();

    const int hp = tid >> 5, n = tid & 31;
    const float* xrow = x + ci * 262144 + (h0 + hp) * 512;
    float a0 = 0.f, a1 = 0.f, a2 = 0.f, pq = 0.f;
    float4 cq = *(float4*)&ws1t[n * 516];
#pragma unroll 4
    for (int k = 0; k < 128; k++) {
        float4 nq = *(float4*)&ws1t[n * 516 + 4 * k + 4];
        float4 x4 = *(const float4*)&xrow[4 * k];
        a1 = fmaf(x4.x, cq.x, a1); a1 = fmaf(x4.y, cq.y, a1);
        a1 = fmaf(x4.z, cq.z, a1); a1 = fmaf(x4.w, cq.w, a1);
        a0 = fmaf(x4.x, cq.y, a0); a0 = fmaf(x4.y, cq.z, a0);
        a0 = fmaf(x4.z, cq.w, a0); a0 = fmaf(x4.w, nq.x, a0);
        a2 = fmaf(x4.x, pq,   a2); a2 = fmaf(x4.y, cq.x, a2);
        a2 = fmaf(x4.z, cq.y, a2); a2 = fmaf(x4.w, cq.z, a2);
        pq = cq.w; cq = nq;
    }
    float* g = ws + OFF_G + v * GSTRIDE + (h0 + hp + 1) * 288 + ci * 96 + n;
    g[0] = a0; g[32] = a1; g[64] = a2;
}

// ---------------------------------------------------------------------------
// k_mlp: per (v, c): y1[h,n] = sigm(b1 + cb*S1 + 27-tap gather from global G),
// stage-2 acc[o] += y1*w2[h][o] over a 128-h chunk, atomicAdd into PS.
// grid (96 cblk, 4 hchunk, 3 v), block 256 (8 channels x 32 n). No LDS.
// w2 rows prefetched one ahead (software pipeline for the scalar loads).
// ---------------------------------------------------------------------------
struct MlpPtrs {
    const float* b1[3];
    const float* w2[3];
    const float* b2[3];
};

__device__ __forceinline__ void gload(float g[27], const float* __restrict__ gv,
                                      int h, int n) {
#pragma unroll
    for (int ci = 0; ci < 3; ci++)
#pragma unroll
        for (int dy = 0; dy < 3; dy++)
#pragma unroll
            for (int dx = 0; dx < 3; dx++)
                g[ci * 9 + dy * 3 + dx] = gv[(h + dy) * 288 + ci * 96 + dx * 32 + n];
}
__device__ __forceinline__ void rd32(float w[32], const float* __restrict__ p) {
#pragma unroll
    for (int o = 0; o < 32; o++) w[o] = p[o];
}
__device__ __forceinline__ float y1val(const float g[27], const float cw[27],
                                       float base) {
    float s0 = base, s1 = 0.f, s2 = 0.f;
#pragma unroll
    for (int j = 0; j < 9; j++) {
        s0 = fmaf(cw[j],      g[j],      s0);
        s1 = fmaf(cw[j + 9],  g[j + 9],  s1);
        s2 = fmaf(cw[j + 18], g[j + 18], s2);
    }
    return sigm((s0 + s1) + s2);
}

__global__ __launch_bounds__(256) void k_mlp(const float* __restrict__ cwp,
                                             const float* __restrict__ cbp,
                                             MlpPtrs mp, float* __restrict__ ws) {
    const int cb = blockIdx.x, hc = blockIdx.y, v = blockIdx.z;
    const int tid = threadIdx.x, cl = tid >> 5, n = tid & 31;
    const int c = cb * 8 + cl;
    const int h0 = hc * 128;

    const float* gv  = ws + OFF_G + v * GSTRIDE;
    const float* w2p = mp.w2[v];

    float cw[27];
#pragma unroll
    for (int j = 0; j < 27; j++) cw[j] = cwp[c * 27 + j];
    const float base = mp.b1[v][n] + cbp[c] * ws[OFF_S1 + v * 32 + n];

    float acc[32];
#pragma unroll
    for (int o = 0; o < 32; o++) acc[o] = 0.f;

    float ga[27], gb[27];
    float w0[32], w1[32];
    gload(ga, gv, h0, n);
    rd32(w0, w2p + h0 * 32);

    for (int hh = 0; hh < 128; hh += 2) {
        const int h = h0 + hh;
        gload(gb, gv, h + 1, n);                 // taps for h+1 (pads cover ends)
        rd32(w1, w2p + (h + 1) * 32);            // prefetch w2 row h+1
        float ya = y1val(ga, cw, base);
#pragma unroll
        for (int o = 0; o < 32; o++) acc[o] = fmaf(ya, w0[o], acc[o]);

        gload(ga, gv, h + 2, n);                 // taps for h+2
        {                                        // prefetch w2 row h+2 (clamped)
            int hn = h + 2 > 511 ? 511 : h + 2;
            rd32(w0, w2p + hn * 32);
        }
        float yb = y1val(gb, cw, base);
#pragma unroll
        for (int o = 0; o < 32; o++) acc[o] = fmaf(yb, w1[o], acc[o]);
    }

    float* ps = ws + OFF_SC + ((v * 768 + c) * 32) * 32;   // [o][n]
#pragma unroll
    for (int o = 0; o < 32; o++) atomicAdd(&ps[o * 32 + n], acc[o]);
}

// ---------------------------------------------------------------------------
// k_mlp2: PS -> +b2 -> sigmoid -> split-heads scatter into QKV.
// ---------------------------------------------------------------------------
__global__ __launch_bounds__(256) void k_mlp2(MlpPtrs mp, float* __restrict__ ws) {
    int i = blockIdx.x * 256 + threadIdx.x;       // over 3*768*32*32
    if (i >= 2359296) return;
    int n = i & 31, o = (i >> 5) & 31;
    int cv = i >> 10;                              // 0..2303
    int c = cv % 768, v = cv / 768;
    float m = sigm(ws[OFF_SC + i] + mp.b2[v][o]);
    int head = ((o & 1) << 1) | (n & 1);           // (head1,head2)
    int sidx = ((o >> 1) << 4) | (n >> 1);         // hidx*16+widx
    ws[OFF_QKV + v * 786432 + head * 196608 + c * 256 + sidx] = m;
}

// ---------------------------------------------------------------------------
// k_qk: scores[head] = temp[head] * Q @ K^T   (768x768, K=256)
// 64x64 tiles, 4x4 micro-tile, LDS tiles stored [k][row] for b128 reads.
// ---------------------------------------------------------------------------
__global__ __launch_bounds__(256) void k_qk(const float* __restrict__ tempr,
                                            float* __restrict__ ws) {
    const int i0 = blockIdx.x * 64, j0 = blockIdx.y * 64, head = blockIdx.z;
    const float* Q = ws + OFF_QKV + head * 196608;             // v=0
    const float* K = ws + OFF_QKV + 786432 + head * 196608;    // v=1
    float* S = ws + OFF_SC + head * 589824;
    const float temp = tempr[head];
    __shared__ __align__(16) float Qs[64][68];
    __shared__ __align__(16) float Ks[64][68];
    const int tid = threadIdx.x, ty = tid >> 4, tx = tid & 15;
    float acc[4][4] = {};

    for (int kc = 0; kc < 256; kc += 64) {
        __syncthreads();
        for (int idx = tid; idx < 1024; idx += 256) {
            int r = idx >> 4, k4 = (idx & 15) * 4;
            float4 q = *(const float4*)&Q[(i0 + r) * 256 + kc + k4];
            Qs[k4 + 0][r] = q.x; Qs[k4 + 1][r] = q.y; Qs[k4 + 2][r] = q.z; Qs[k4 + 3][r] = q.w;
            float4 k = *(const float4*)&K[(j0 + r) * 256 + kc + k4];
            Ks[k4 + 0][r] = k.x; Ks[k4 + 1][r] = k.y; Ks[k4 + 2][r] = k.z; Ks[k4 + 3][r] = k.w;
        }
        __syncthreads();
#pragma unroll
        for (int k = 0; k < 64; k++) {
            float4 a = *(float4*)&Qs[k][ty * 4];
            float4 b = *(float4*)&Ks[k][tx * 4];
            float av[4] = {a.x, a.y, a.z, a.w}, bv[4] = {b.x, b.y, b.z, b.w};
#pragma unroll
            for (int e = 0; e < 4; e++)
#pragma unroll
                for (int f = 0; f < 4; f++) acc[e][f] = fmaf(av[e], bv[f], acc[e][f]);
        }
    }
#pragma unroll
    for (int e = 0; e < 4; e++) {
        float4 r = make_float4(acc[e][0] * temp, acc[e][1] * temp,
                               acc[e][2] * temp, acc[e][3] * temp);
        *(float4*)&S[(i0 + ty * 4 + e) * 768 + j0 + tx * 4] = r;
    }
}

// ---------------------------------------------------------------------------
// k_soft: row softmax over 768. One wave per row.
// ---------------------------------------------------------------------------
__global__ __launch_bounds__(64) void k_soft(float* __restrict__ ws) {
    float* row = ws + OFF_SC + (size_t)blockIdx.x * 768;
    const int t = threadIdx.x;
    float4 v0 = *(float4*)&row[t * 12];
    float4 v1 = *(float4*)&row[t * 12 + 4];
    float4 v2 = *(float4*)&row[t * 12 + 8];
    float m0 = fmaxf(fmaxf(v0.x, v0.y), fmaxf(v0.z, v0.w));
    float m1 = fmaxf(fmaxf(v1.x, v1.y), fmaxf(v1.z, v1.w));
    float m2 = fmaxf(fmaxf(v2.x, v2.y), fmaxf(v2.z, v2.w));
    float m = fmaxf(fmaxf(m0, m1), m2);
#pragma unroll
    for (int off = 32; off > 0; off >>= 1) m = fmaxf(m, __shfl_xor(m, off));
    v0.x = __expf(v0.x - m); v0.y = __expf(v0.y - m); v0.z = __expf(v0.z - m); v0.w = __expf(v0.w - m);
    v1.x = __expf(v1.x - m); v1.y = __expf(v1.y - m); v1.z = __expf(v1.z - m); v1.w = __expf(v1.w - m);
    v2.x = __expf(v2.x - m); v2.y = __expf(v2.y - m); v2.z = __expf(v2.z - m); v2.w = __expf(v2.w - m);
    float s = v0.x + v0.y + v0.z + v0.w + v1.x + v1.y + v1.z + v1.w + v2.x + v2.y + v2.z + v2.w;
#pragma unroll
    for (int off = 32; off > 0; off >>= 1) s += __shfl_xor(s, off);
    float inv = __builtin_amdgcn_rcpf(s);
    v0.x *= inv; v0.y *= inv; v0.z *= inv; v0.w *= inv;
    v1.x *= inv; v1.y *= inv; v1.z *= inv; v1.w *= inv;
    v2.x *= inv; v2.y *= inv; v2.z *= inv; v2.w *= inv;
    *(float4*)&row[t * 12]     = v0;
    *(float4*)&row[t * 12 + 4] = v1;
    *(float4*)&row[t * 12 + 8] = v2;
}

// ---------------------------------------------------------------------------
// k_av: ATT[head] = attn @ V  (768x256, K=768). 32x64 tiles (384 blocks),
// 2x4 micro-tile.
// ---------------------------------------------------------------------------
__global__ __launch_bounds__(256) void k_av(float* __restrict__ ws) {
    const int i0 = blockIdx.x * 32, s0 = blockIdx.y * 64, head = blockIdx.z;
    const float* A = ws + OFF_SC + head * 589824;
    const float* V = ws + OFF_QKV + 2 * 786432 + head * 196608;
    float* O = ws + OFF_ATT + head * 196608;
    __shared__ __align__(16) float As[64][34];
    __shared__ __align__(16) float Bs[64][68];
    const int tid = threadIdx.x, ty = tid >> 4, tx = tid & 15;
    float acc[2][4] = {};

    for (int dc = 0; dc < 768; dc += 64) {
        __syncthreads();
        for (int idx = tid; idx < 512; idx += 256) {
            int r = idx >> 4, k4 = (idx & 15) * 4;
            float4 a = *(const float4*)&A[(i0 + r) * 768 + dc + k4];
            As[k4 + 0][r] = a.x; As[k4 + 1][r] = a.y; As[k4 + 2][r] = a.z; As[k4 + 3][r] = a.w;
        }
        for (int idx = tid; idx < 1024; idx += 256) {
            int r = idx >> 4, k4 = (idx & 15) * 4;
            *(float4*)&Bs[r][k4] = *(const float4*)&V[(dc + r) * 256 + s0 + k4];
        }
        __syncthreads();
#pragma unroll
        for (int k = 0; k < 64; k++) {
            float a0 = As[k][ty * 2], a1 = As[k][ty * 2 + 1];
            float4 b = *(float4*)&Bs[k][tx * 4];
            acc[0][0] = fmaf(a0, b.x, acc[0][0]); acc[0][1] = fmaf(a0, b.y, acc[0][1]);
            acc[0][2] = fmaf(a0, b.z, acc[0][2]); acc[0][3] = fmaf(a0, b.w, acc[0][3]);
            acc[1][0] = fmaf(a1, b.x, acc[1][0]); acc[1][1] = fmaf(a1, b.y, acc[1][1]);
            acc[1][2] = fmaf(a1, b.z, acc[1][2]); acc[1][3] = fmaf(a1, b.w, acc[1][3]);
        }
    }
#pragma unroll
    for (int e = 0; e < 2; e++) {
        float4 r = make_float4(acc[e][0], acc[e][1], acc[e][2], acc[e][3]);
        *(float4*)&O[(i0 + ty * 2 + e) * 256 + s0 + tx * 4] = r;
    }
}

// ---------------------------------------------------------------------------
// k_ffn: fused pointwise(3->12) + dwconv3x3 + gelu-gate + pointwise(6->3)
// + residual, f32 store. 32x32 pixel tiles, 34x34 halo in LDS.
// ---------------------------------------------------------------------------
struct FfnPtrs { const float* p[6]; };  // pi_w, pi_b, dw_w, dw_b, po_w, po_b

__global__ __launch_bounds__(256) void k_ffn(const float* __restrict__ ws,
                                             const float* __restrict__ x,
                                             FfnPtrs fp,
                                             float* __restrict__ out) {
    const int x0 = blockIdx.x * 32, y0 = blockIdx.y * 32;
    __shared__ float wsm[192];
    __shared__ float p[12][1156];
    const int tid = threadIdx.x;
    if (tid < 36)       wsm[tid] = fp.p[0][tid];          // pi_w (12,3)
    else if (tid < 48)  wsm[tid] = fp.p[1][tid - 36];     // pi_b (12)
    else if (tid < 156) wsm[tid] = fp.p[2][tid - 48];     // dw_w (12,9)
    else if (tid < 168) wsm[tid] = fp.p[3][tid - 156];    // dw_b (12)
    else if (tid < 186) wsm[tid] = fp.p[4][tid - 168];    // po_w (3,6)
    else if (tid < 189) wsm[tid] = fp.p[5][tid - 186];    // po_b (3)
    __syncthreads();

    const float* A = ws + OFF_ATT;
    for (int i = tid; i < 1156; i += 256) {
        int py = i / 34, px = i % 34;
        int gy = y0 + py - 1, gx = x0 + px - 1;
        bool in = ((unsigned)gy < 512u) && ((unsigned)gx < 512u);
        float a0 = 0.f, a1 = 0.f, a2 = 0.f;
        if (in) {
            int b = gy * 512 + gx;
            a0 = A[b]; a1 = A[262144 + b]; a2 = A[524288 + b];
        }
#pragma unroll
        for (int j = 0; j < 12; j++) {
            float t = in ? (wsm[36 + j] + wsm[j * 3] * a0 + wsm[j * 3 + 1] * a1
                            + wsm[j * 3 + 2] * a2)
                         : 0.f;
            p[j][i] = t;
        }
    }
    __syncthreads();

#pragma unroll
    for (int it = 0; it < 4; it++) {
        int pl = tid + it * 256;
        int ly = pl >> 5, lx = pl & 31;
        float z[12];
#pragma unroll
        for (int j = 0; j < 12; j++) {
            const float* dw = &wsm[48 + j * 9];
            const float* pr = &p[j][ly * 34 + lx];
            z[j] = wsm[156 + j]
                 + dw[0] * pr[0]  + dw[1] * pr[1]  + dw[2] * pr[2]
                 + dw[3] * pr[34] + dw[4] * pr[35] + dw[5] * pr[36]
                 + dw[6] * pr[68] + dw[7] * pr[69] + dw[8] * pr[70];
        }
        float g[6];
#pragma unroll
        for (int j = 0; j < 6; j++) {
            float xx = z[j];
            g[j] = 0.5f * xx * (1.f + erff(xx * 0.70710678118f)) * z[6 + j];
        }
        int b = (y0 + ly) * 512 + (x0 + lx);
#pragma unroll
        for (int co = 0; co < 3; co++) {
            float r = wsm[186 + co];
#pragma unroll
            for (int j = 0; j < 6; j++) r = fmaf(wsm[168 + co * 6 + j], g[j], r);
            r += x[co * 262144 + b];             // residual
            out[co * 262144 + b] = r;
        }
    }
}

// ---------------------------------------------------------------------------
extern "C" void kernel_launch(void* const* d_in, const int* in_sizes, int n_in,
                              void* d_out, int out_size, void* d_ws, size_t ws_size,
                              hipStream_t stream) {
    float* ws = (float*)d_ws;
    float* out = (float*)d_out;
    const float* x   = (const float*)d_in[0];
    const float* cw  = (const float*)d_in[1];
    const float* cb  = (const float*)d_in[2];
    const float* qw1 = (const float*)d_in[3];
    const float* kw1 = (const float*)d_in[7];
    const float* vw1 = (const float*)d_in[11];
    const float* temp= (const float*)d_in[15];

    MlpPtrs mp;
    mp.b1[0] = (const float*)d_in[4];  mp.w2[0] = (const float*)d_in[5];  mp.b2[0] = (const float*)d_in[6];
    mp.b1[1] = (const float*)d_in[8];  mp.w2[1] = (const float*)d_in[9];  mp.b2[1] = (const float*)d_in[10];
    mp.b1[2] = (const float*)d_in[12]; mp.w2[2] = (const float*)d_in[13]; mp.b2[2] = (const float*)d_in[14];

    FfnPtrs fp;
    for (int i = 0; i < 6; i++) fp.p[i] = (const float*)d_in[16 + i];

    k_prep<<<9251, 256, 0, stream>>>(qw1, kw1, vw1, ws);
    k_corr<<<dim3(64, 3, 3), 256, 0, stream>>>(x, qw1, kw1, vw1, ws);
    k_mlp <<<dim3(96, 4, 3), 256, 0, stream>>>(cw, cb, mp, ws);
    k_mlp2<<<9216, 256, 0, stream>>>(mp, ws);
    k_qk  <<<dim3(12, 12, 4), 256, 0, stream>>>(temp, ws);
    k_soft<<<3072, 64, 0, stream>>>(ws);
    k_av  <<<dim3(24, 4, 4), 256, 0, stream>>>(ws);
    k_ffn <<<dim3(16, 16), 256, 0, stream>>>(ws, x, fp, out);
}

// Round 6
// 326.429 us; speedup vs baseline: 1.5842x; 1.0539x over previous
//
#include <hip/hip_runtime.h>
#include <math.h>

// ---------------------------------------------------------------------------
// Restormer block, B=1 DIM=3 NC=512 HEADS=2 -> CT=768, NT=32, HID=6. f32 I/O.
//
// conv3x3 (+) MLP-stage1 collapsed through G[ci,h,dx,n] = row-correlations of
// x with w1 columns (1.8 MB instead of the 805 MB conv output t).
// R6: k_mlp tap loads cut 27->9 per h via a rolling 4-slot register row file
// (R[4][9] holds G-rows h..h+3; 4-phase unrolled body, constant indices ->
// register renaming, no v_movs). w2 scalar pipeline kept. k_mlp2 re-indexed
// by OUTPUT element so QKV writes are fully coalesced (scatter moved to the
// read side at stride-8B).
// ---------------------------------------------------------------------------

__device__ __forceinline__ float sigm(float s) {
    return __builtin_amdgcn_rcpf(1.f + __expf(-s));
}

// ---- f32 workspace layout (element offsets) -------------------------------
static constexpr int OFF_G   = 0;         // [3v][515 rows][3ci][3dx][32n]; rows 0,513,514 zero pad
static constexpr int GSTRIDE = 148320;    // 515*288
static constexpr int OFF_S1  = 444960;    // [3v][32] column sums of w1
static constexpr int OFF_QKV = 445056;    // [3v][4head][768c][256s]
static constexpr int OFF_SC  = 2804352;   // [4head][768][768]; ALSO pre-sigmoid PS [3v][768c][32o][32n]
static constexpr int OFF_ATT = 5163648;   // [4head][768][256] == (3,512,512) flat
// total 5950080 floats = 23.8 MB

// ---------------------------------------------------------------------------
// k_prep: zero G pad rows; S1[v][n] = sum_u w1v[u][n]; zero PS accumulator.
// ---------------------------------------------------------------------------
__global__ __launch_bounds__(256) void k_prep(const float* __restrict__ qw1,
                                              const float* __restrict__ kw1,
                                              const float* __restrict__ vw1,
                                              float* __restrict__ ws) {
    int i = blockIdx.x * 256 + threadIdx.x;
    if (i < 2592) {                        // zero G pad rows 0,513,514 per v
        int v = i / 864, rr = (i % 864) / 288, col = i % 288;
        int row = (rr == 0) ? 0 : (512 + rr);
        ws[OFF_G + v * GSTRIDE + row * 288 + col] = 0.f;
    } else if (i >= 2624 && i < 8768) {    // S1: 96 waves, shuffle-reduce
        int j = i - 2624;
        int w = j >> 6, lane = j & 63;
        int v = w >> 5, n = w & 31;
        const float* w1p = (v == 0) ? qw1 : ((v == 1) ? kw1 : vw1);
        float s = 0.f;
#pragma unroll
        for (int k = 0; k < 8; k++) s += w1p[(lane + 64 * k) * 32 + n];
#pragma unroll
        for (int off = 32; off > 0; off >>= 1) s += __shfl_xor(s, off);
        if (lane == 0) ws[OFF_S1 + w] = s;
    } else if (i >= 8768 && i < 8768 + 2359296) {
        ws[OFF_SC + (i - 8768)] = 0.f;     // PS init
    }
}

// ---------------------------------------------------------------------------
// k_corr: G[v][h+1][ci][dx][n] = sum_u x[ci][h][u] * w1v[u+1-dx][n]
// grid (64 hblk, 3 ci, 3 v), block 256 = 8 rows x 32 n.
// ---------------------------------------------------------------------------
__global__ __launch_bounds__(256) void k_corr(const float* __restrict__ x,
                                              const float* __restrict__ qw1,
                                              const float* __restrict__ kw1,
                                              const float* __restrict__ vw1,
                                              float* __restrict__ ws) {
    const int h0 = blockIdx.x * 8, ci = blockIdx.y, v = blockIdx.z;
    const int tid = threadIdx.x;
    __shared__ __align__(16) float ws1t[32 * 516];

    const float* w1f = (v == 0) ? qw1 : ((v == 1) ? kw1 : vw1);
    for (int i = tid; i < 4096; i += 256) {       // transpose-stage w1
        int n_ = i & 31, u = (i >> 5) * 4;
        float a = w1f[(u + 0) * 32 + n_];
        float b = w1f[(u + 1) * 32 + n_];
        float c = w1f[(u + 2) * 32 + n_];
        float d = w1f[(u + 3) * 32 + n_];
        *(float4*)&ws1t[n_ * 516 + u] = make_float4(a, b, c, d);
    }
    if (tid < 32) *(float4*)&ws1t[tid * 516 + 512] = make_float4(0.f, 0.f, 0.f, 0.f);
    __syncthreads();

    const int hp = tid >> 5, n = tid & 31;
    const float* xrow = x + ci * 262144 + (h0 + hp) * 512;
    float a0 = 0.f, a1 = 0.f, a2 = 0.f, pq = 0.f;
    float4 cq = *(float4*)&ws1t[n * 516];
#pragma unroll 4
    for (int k = 0; k < 128; k++) {
        float4 nq = *(float4*)&ws1t[n * 516 + 4 * k + 4];
        float4 x4 = *(const float4*)&xrow[4 * k];
        a1 = fmaf(x4.x, cq.x, a1); a1 = fmaf(x4.y, cq.y, a1);
        a1 = fmaf(x4.z, cq.z, a1); a1 = fmaf(x4.w, cq.w, a1);
        a0 = fmaf(x4.x, cq.y, a0); a0 = fmaf(x4.y, cq.z, a0);
        a0 = fmaf(x4.z, cq.w, a0); a0 = fmaf(x4.w, nq.x, a0);
        a2 = fmaf(x4.x, pq,   a2); a2 = fmaf(x4.y, cq.x, a2);
        a2 = fmaf(x4.z, cq.y, a2); a2 = fmaf(x4.w, cq.z, a2);
        pq = cq.w; cq = nq;
    }
    float* g = ws + OFF_G + v * GSTRIDE + (h0 + hp + 1) * 288 + ci * 96 + n;
    g[0] = a0; g[32] = a1; g[64] = a2;
}

// ---------------------------------------------------------------------------
// k_mlp: per (v, c): y1[h,n] = sigm(b1 + cb*S1 + 27-tap gather from G),
// stage-2 acc[o] += y1*w2[h][o] over a 128-h chunk, atomicAdd into PS.
// grid (96 cblk, 4 hchunk, 3 v), block 256 (8 channels x 32 n). No LDS.
// Rolling 4-slot tap rows: R[s] holds G-row (h0+4m+s); each output h uses
// slots k,k+1,k+2 (mod 4) then refills slot k with row h+4 -> 9 loads/h.
// w2 rows prefetched one ahead into alternating SGPR buffers.
// ---------------------------------------------------------------------------
struct MlpPtrs {
    const float* b1[3];
    const float* w2[3];
    const float* b2[3];
};

__device__ __forceinline__ void rd32(float w[32], const float* __restrict__ p) {
#pragma unroll
    for (int o = 0; o < 32; o++) w[o] = p[o];
}
__device__ __forceinline__ void rdrow(float R[9], const float* __restrict__ rp) {
#pragma unroll
    for (int q = 0; q < 9; q++) R[q] = rp[(q / 3) * 96 + (q % 3) * 32];
}

__global__ __launch_bounds__(256) void k_mlp(const float* __restrict__ cwp,
                                             const float* __restrict__ cbp,
                                             MlpPtrs mp, float* __restrict__ ws) {
    const int cb = blockIdx.x, hc = blockIdx.y, v = blockIdx.z;
    const int tid = threadIdx.x, cl = tid >> 5, n = tid & 31;
    const int c = cb * 8 + cl;
    const int h0 = hc * 128;

    const float* gv  = ws + OFF_G + v * GSTRIDE;
    const float* w2p = mp.w2[v];

    float cwr[3][9];                                // [dy][ci*3+dx]
#pragma unroll
    for (int dy = 0; dy < 3; dy++)
#pragma unroll
        for (int q = 0; q < 9; q++)
            cwr[dy][q] = cwp[c * 27 + (q / 3) * 9 + dy * 3 + (q % 3)];
    const float base = mp.b1[v][n] + cbp[c] * ws[OFF_S1 + v * 32 + n];

    float acc[32];
#pragma unroll
    for (int o = 0; o < 32; o++) acc[o] = 0.f;

    float R[4][9];
    const float* rp = gv + h0 * 288 + n;            // G-row h0, this lane's n
#pragma unroll
    for (int r = 0; r < 4; r++) rdrow(R[r], rp + r * 288);
    rp += 4 * 288;                                  // next row to fetch: h0+4

    float wbuf[2][32];
    rd32(wbuf[0], w2p + h0 * 32);

    for (int hb = 0; hb < 32; hb++) {
#pragma unroll
        for (int k = 0; k < 4; k++) {
            const int h = h0 + hb * 4 + k;
            // prefetch next w2 row (wave-uniform -> scalar loads)
            int hn = h + 1; if (hn > 511) hn = 511;
            rd32(wbuf[(k + 1) & 1], w2p + hn * 32);
            // taps: rows h,h+1,h+2 live in slots k, k+1, k+2 (mod 4)
            float s0 = base, s1 = 0.f, s2 = 0.f;
#pragma unroll
            for (int q = 0; q < 9; q++) {
                s0 = fmaf(cwr[0][q], R[(k + 0) & 3][q], s0);
                s1 = fmaf(cwr[1][q], R[(k + 1) & 3][q], s1);
                s2 = fmaf(cwr[2][q], R[(k + 2) & 3][q], s2);
            }
            // refill freed slot k with G-row h+4 (in-bounds of ws; values
            // past the chunk are loaded but never consumed)
            rdrow(R[k & 3], rp + k * 288);
            float y = sigm((s0 + s1) + s2);
#pragma unroll
            for (int o = 0; o < 32; o++) acc[o] = fmaf(y, wbuf[k & 1][o], acc[o]);
        }
        rp += 4 * 288;
    }

    float* ps = ws + OFF_SC + ((v * 768 + c) * 32) * 32;   // [o][n]
#pragma unroll
    for (int o = 0; o < 32; o++) atomicAdd(&ps[o * 32 + n], acc[o]);
}

// ---------------------------------------------------------------------------
// k_mlp2: PS -> +b2 -> sigmoid -> split-heads scatter into QKV.
// Output-indexed: thread i = (v, head, c, sidx) -> coalesced QKV writes;
// the permutation lands on the PS read side (stride-8B, L2-resident).
// ---------------------------------------------------------------------------
__global__ __launch_bounds__(256) void k_mlp2(MlpPtrs mp, float* __restrict__ ws) {
    int i = blockIdx.x * 256 + threadIdx.x;       // over 3*4*768*256
    if (i >= 2359296) return;
    int sidx = i & 255;
    int r = i >> 8;                                // v*3072 + head*768 + c
    int c = r % 768;
    int head = (r / 768) & 3;
    int v = r / 3072;
    int o = ((sidx >> 4) << 1) | (head >> 1);
    int n = ((sidx & 15) << 1) | (head & 1);
    float m = sigm(ws[OFF_SC + ((v * 768 + c) * 32 + o) * 32 + n] + mp.b2[v][o]);
    ws[OFF_QKV + v * 786432 + head * 196608 + c * 256 + sidx] = m;
}

// ---------------------------------------------------------------------------
// k_qk: scores[head] = temp[head] * Q @ K^T   (768x768, K=256)
// 64x64 tiles, 4x4 micro-tile, LDS tiles stored [k][row] for b128 reads.
// ---------------------------------------------------------------------------
__global__ __launch_bounds__(256) void k_qk(const float* __restrict__ tempr,
                                            float* __restrict__ ws) {
    const int i0 = blockIdx.x * 64, j0 = blockIdx.y * 64, head = blockIdx.z;
    const float* Q = ws + OFF_QKV + head * 196608;             // v=0
    const float* K = ws + OFF_QKV + 786432 + head * 196608;    // v=1
    float* S = ws + OFF_SC + head * 589824;
    const float temp = tempr[head];
    __shared__ __align__(16) float Qs[64][68];
    __shared__ __align__(16) float Ks[64][68];
    const int tid = threadIdx.x, ty = tid >> 4, tx = tid & 15;
    float acc[4][4] = {};

    for (int kc = 0; kc < 256; kc += 64) {
        __syncthreads();
        for (int idx = tid; idx < 1024; idx += 256) {
            int r = idx >> 4, k4 = (idx & 15) * 4;
            float4 q = *(const float4*)&Q[(i0 + r) * 256 + kc + k4];
            Qs[k4 + 0][r] = q.x; Qs[k4 + 1][r] = q.y; Qs[k4 + 2][r] = q.z; Qs[k4 + 3][r] = q.w;
            float4 k = *(const float4*)&K[(j0 + r) * 256 + kc + k4];
            Ks[k4 + 0][r] = k.x; Ks[k4 + 1][r] = k.y; Ks[k4 + 2][r] = k.z; Ks[k4 + 3][r] = k.w;
        }
        __syncthreads();
#pragma unroll
        for (int k = 0; k < 64; k++) {
            float4 a = *(float4*)&Qs[k][ty * 4];
            float4 b = *(float4*)&Ks[k][tx * 4];
            float av[4] = {a.x, a.y, a.z, a.w}, bv[4] = {b.x, b.y, b.z, b.w};
#pragma unroll
            for (int e = 0; e < 4; e++)
#pragma unroll
                for (int f = 0; f < 4; f++) acc[e][f] = fmaf(av[e], bv[f], acc[e][f]);
        }
    }
#pragma unroll
    for (int e = 0; e < 4; e++) {
        float4 r = make_float4(acc[e][0] * temp, acc[e][1] * temp,
                               acc[e][2] * temp, acc[e][3] * temp);
        *(float4*)&S[(i0 + ty * 4 + e) * 768 + j0 + tx * 4] = r;
    }
}

// ---------------------------------------------------------------------------
// k_soft: row softmax over 768. One wave per row.
// ---------------------------------------------------------------------------
__global__ __launch_bounds__(64) void k_soft(float* __restrict__ ws) {
    float* row = ws + OFF_SC + (size_t)blockIdx.x * 768;
    const int t = threadIdx.x;
    float4 v0 = *(float4*)&row[t * 12];
    float4 v1 = *(float4*)&row[t * 12 + 4];
    float4 v2 = *(float4*)&row[t * 12 + 8];
    float m0 = fmaxf(fmaxf(v0.x, v0.y), fmaxf(v0.z, v0.w));
    float m1 = fmaxf(fmaxf(v1.x, v1.y), fmaxf(v1.z, v1.w));
    float m2 = fmaxf(fmaxf(v2.x, v2.y), fmaxf(v2.z, v2.w));
    float m = fmaxf(fmaxf(m0, m1), m2);
#pragma unroll
    for (int off = 32; off > 0; off >>= 1) m = fmaxf(m, __shfl_xor(m, off));
    v0.x = __expf(v0.x - m); v0.y = __expf(v0.y - m); v0.z = __expf(v0.z - m); v0.w = __expf(v0.w - m);
    v1.x = __expf(v1.x - m); v1.y = __expf(v1.y - m); v1.z = __expf(v1.z - m); v1.w = __expf(v1.w - m);
    v2.x = __expf(v2.x - m); v2.y = __expf(v2.y - m); v2.z = __expf(v2.z - m); v2.w = __expf(v2.w - m);
    float s = v0.x + v0.y + v0.z + v0.w + v1.x + v1.y + v1.z + v1.w + v2.x + v2.y + v2.z + v2.w;
#pragma unroll
    for (int off = 32; off > 0; off >>= 1) s += __shfl_xor(s, off);
    float inv = __builtin_amdgcn_rcpf(s);
    v0.x *= inv; v0.y *= inv; v0.z *= inv; v0.w *= inv;
    v1.x *= inv; v1.y *= inv; v1.z *= inv; v1.w *= inv;
    v2.x *= inv; v2.y *= inv; v2.z *= inv; v2.w *= inv;
    *(float4*)&row[t * 12]     = v0;
    *(float4*)&row[t * 12 + 4] = v1;
    *(float4*)&row[t * 12 + 8] = v2;
}

// ---------------------------------------------------------------------------
// k_av: ATT[head] = attn @ V  (768x256, K=768). 32x64 tiles (384 blocks),
// 2x4 micro-tile.
// ---------------------------------------------------------------------------
__global__ __launch_bounds__(256) void k_av(float* __restrict__ ws) {
    const int i0 = blockIdx.x * 32, s0 = blockIdx.y * 64, head = blockIdx.z;
    const float* A = ws + OFF_SC + head * 589824;
    const float* V = ws + OFF_QKV + 2 * 786432 + head * 196608;
    float* O = ws + OFF_ATT + head * 196608;
    __shared__ __align__(16) float As[64][34];
    __shared__ __align__(16) float Bs[64][68];
    const int tid = threadIdx.x, ty = tid >> 4, tx = tid & 15;
    float acc[2][4] = {};

    for (int dc = 0; dc < 768; dc += 64) {
        __syncthreads();
        for (int idx = tid; idx < 512; idx += 256) {
            int r = idx >> 4, k4 = (idx & 15) * 4;
            float4 a = *(const float4*)&A[(i0 + r) * 768 + dc + k4];
            As[k4 + 0][r] = a.x; As[k4 + 1][r] = a.y; As[k4 + 2][r] = a.z; As[k4 + 3][r] = a.w;
        }
        for (int idx = tid; idx < 1024; idx += 256) {
            int r = idx >> 4, k4 = (idx & 15) * 4;
            *(float4*)&Bs[r][k4] = *(const float4*)&V[(dc + r) * 256 + s0 + k4];
        }
        __syncthreads();
#pragma unroll
        for (int k = 0; k < 64; k++) {
            float a0 = As[k][ty * 2], a1 = As[k][ty * 2 + 1];
            float4 b = *(float4*)&Bs[k][tx * 4];
            acc[0][0] = fmaf(a0, b.x, acc[0][0]); acc[0][1] = fmaf(a0, b.y, acc[0][1]);
            acc[0][2] = fmaf(a0, b.z, acc[0][2]); acc[0][3] = fmaf(a0, b.w, acc[0][3]);
            acc[1][0] = fmaf(a1, b.x, acc[1][0]); acc[1][1] = fmaf(a1, b.y, acc[1][1]);
            acc[1][2] = fmaf(a1, b.z, acc[1][2]); acc[1][3] = fmaf(a1, b.w, acc[1][3]);
        }
    }
#pragma unroll
    for (int e = 0; e < 2; e++) {
        float4 r = make_float4(acc[e][0], acc[e][1], acc[e][2], acc[e][3]);
        *(float4*)&O[(i0 + ty * 2 + e) * 256 + s0 + tx * 4] = r;
    }
}

// ---------------------------------------------------------------------------
// k_ffn: fused pointwise(3->12) + dwconv3x3 + gelu-gate + pointwise(6->3)
// + residual, f32 store. 32x32 pixel tiles, 34x34 halo in LDS.
// ---------------------------------------------------------------------------
struct FfnPtrs { const float* p[6]; };  // pi_w, pi_b, dw_w, dw_b, po_w, po_b

__global__ __launch_bounds__(256) void k_ffn(const float* __restrict__ ws,
                                             const float* __restrict__ x,
                                             FfnPtrs fp,
                                             float* __restrict__ out) {
    const int x0 = blockIdx.x * 32, y0 = blockIdx.y * 32;
    __shared__ float wsm[192];
    __shared__ float p[12][1156];
    const int tid = threadIdx.x;
    if (tid < 36)       wsm[tid] = fp.p[0][tid];          // pi_w (12,3)
    else if (tid < 48)  wsm[tid] = fp.p[1][tid - 36];     // pi_b (12)
    else if (tid < 156) wsm[tid] = fp.p[2][tid - 48];     // dw_w (12,9)
    else if (tid < 168) wsm[tid] = fp.p[3][tid - 156];    // dw_b (12)
    else if (tid < 186) wsm[tid] = fp.p[4][tid - 168];    // po_w (3,6)
    else if (tid < 189) wsm[tid] = fp.p[5][tid - 186];    // po_b (3)
    __syncthreads();

    const float* A = ws + OFF_ATT;
    for (int i = tid; i < 1156; i += 256) {
        int py = i / 34, px = i % 34;
        int gy = y0 + py - 1, gx = x0 + px - 1;
        bool in = ((unsigned)gy < 512u) && ((unsigned)gx < 512u);
        float a0 = 0.f, a1 = 0.f, a2 = 0.f;
        if (in) {
            int b = gy * 512 + gx;
            a0 = A[b]; a1 = A[262144 + b]; a2 = A[524288 + b];
        }
#pragma unroll
        for (int j = 0; j < 12; j++) {
            float t = in ? (wsm[36 + j] + wsm[j * 3] * a0 + wsm[j * 3 + 1] * a1
                            + wsm[j * 3 + 2] * a2)
                         : 0.f;
            p[j][i] = t;
        }
    }
    __syncthreads();

#pragma unroll
    for (int it = 0; it < 4; it++) {
        int pl = tid + it * 256;
        int ly = pl >> 5, lx = pl & 31;
        float z[12];
#pragma unroll
        for (int j = 0; j < 12; j++) {
            const float* dw = &wsm[48 + j * 9];
            const float* pr = &p[j][ly * 34 + lx];
            z[j] = wsm[156 + j]
                 + dw[0] * pr[0]  + dw[1] * pr[1]  + dw[2] * pr[2]
                 + dw[3] * pr[34] + dw[4] * pr[35] + dw[5] * pr[36]
                 + dw[6] * pr[68] + dw[7] * pr[69] + dw[8] * pr[70];
        }
        float g[6];
#pragma unroll
        for (int j = 0; j < 6; j++) {
            float xx = z[j];
            g[j] = 0.5f * xx * (1.f + erff(xx * 0.70710678118f)) * z[6 + j];
        }
        int b = (y0 + ly) * 512 + (x0 + lx);
#pragma unroll
        for (int co = 0; co < 3; co++) {
            float r = wsm[186 + co];
#pragma unroll
            for (int j = 0; j < 6; j++) r = fmaf(wsm[168 + co * 6 + j], g[j], r);
            r += x[co * 262144 + b];             // residual
            out[co * 262144 + b] = r;
        }
    }
}

// ---------------------------------------------------------------------------
extern "C" void kernel_launch(void* const* d_in, const int* in_sizes, int n_in,
                              void* d_out, int out_size, void* d_ws, size_t ws_size,
                              hipStream_t stream) {
    float* ws = (float*)d_ws;
    float* out = (float*)d_out;
    const float* x   = (const float*)d_in[0];
    const float* cw  = (const float*)d_in[1];
    const float* cb  = (const float*)d_in[2];
    const float* qw1 = (const float*)d_in[3];
    const float* kw1 = (const float*)d_in[7];
    const float* vw1 = (const float*)d_in[11];
    const float* temp= (const float*)d_in[15];

    MlpPtrs mp;
    mp.b1[0] = (const float*)d_in[4];  mp.w2[0] = (const float*)d_in[5];  mp.b2[0] = (const float*)d_in[6];
    mp.b1[1] = (const float*)d_in[8];  mp.w2[1] = (const float*)d_in[9];  mp.b2[1] = (const float*)d_in[10];
    mp.b1[2] = (const float*)d_in[12]; mp.w2[2] = (const float*)d_in[13]; mp.b2[2] = (const float*)d_in[14];

    FfnPtrs fp;
    for (int i = 0; i < 6; i++) fp.p[i] = (const float*)d_in[16 + i];

    k_prep<<<9251, 256, 0, stream>>>(qw1, kw1, vw1, ws);
    k_corr<<<dim3(64, 3, 3), 256, 0, stream>>>(x, qw1, kw1, vw1, ws);
    k_mlp <<<dim3(96, 4, 3), 256, 0, stream>>>(cw, cb, mp, ws);
    k_mlp2<<<9216, 256, 0, stream>>>(mp, ws);
    k_qk  <<<dim3(12, 12, 4), 256, 0, stream>>>(temp, ws);
    k_soft<<<3072, 64, 0, stream>>>(ws);
    k_av  <<<dim3(24, 4, 4), 256, 0, stream>>>(ws);
    k_ffn <<<dim3(16, 16), 256, 0, stream>>>(ws, x, fp, out);
}